// Round 4
// baseline (1189.556 us; speedup 1.0000x reference)
//
#include <hip/hip_runtime.h>
#include <hip/hip_bf16.h>

typedef __attribute__((ext_vector_type(8))) short short8;
typedef __attribute__((ext_vector_type(4))) float f32x4;
typedef __attribute__((ext_vector_type(16))) float f32x16;

constexpr int B = 32, C = 64, HW = 4096;

__device__ __forceinline__ unsigned short f2bf(float f) {
    __hip_bfloat16 h = __float2bfloat16(f);
    unsigned short u; __builtin_memcpy(&u, &h, 2); return u;
}
__device__ __forceinline__ float b2f(unsigned short u) {
    unsigned int t = ((unsigned int)u) << 16; float f; __builtin_memcpy(&f, &t, 4); return f;
}

// ---------------- NCHW f32 -> NHWC bf16 transpose (+ fused attention logits) ----------------
__global__ __launch_bounds__(256) void tr_k(const float* __restrict__ out1,
                                            const float* __restrict__ out2,
                                            const float* __restrict__ out3,
                                            const float* __restrict__ lin_w,
                                            const float* __restrict__ lin_b,
                                            unsigned short* __restrict__ t1,
                                            unsigned short* __restrict__ tp,
                                            float* __restrict__ logits)
{
    int t = threadIdx.x;
    int px = blockIdx.x * 256 + t;
    int b = blockIdx.y;
    if (blockIdx.z == 0) {
        const float* src = out1 + (size_t)b * 64 * HW + px;
        const float* lwp = lin_w + (size_t)px * 64;
        float acc = lin_b[px];
        unsigned short v[64];
#pragma unroll
        for (int c = 0; c < 64; c += 4) {
            float4 w4 = *(const float4*)(lwp + c);
            float x0 = src[(size_t)c * HW];
            float x1 = src[(size_t)(c + 1) * HW];
            float x2 = src[(size_t)(c + 2) * HW];
            float x3 = src[(size_t)(c + 3) * HW];
            acc = fmaf(x0, w4.x, acc); acc = fmaf(x1, w4.y, acc);
            acc = fmaf(x2, w4.z, acc); acc = fmaf(x3, w4.w, acc);
            v[c] = f2bf(x0); v[c + 1] = f2bf(x1); v[c + 2] = f2bf(x2); v[c + 3] = f2bf(x3);
        }
        unsigned short* dst = t1 + ((size_t)b * HW + px) * 64;
#pragma unroll
        for (int j = 0; j < 8; ++j)
            *(short8*)(dst + j * 8) = *(short8*)(v + j * 8);
        logits[(size_t)b * HW + px] = acc;
    } else {
        const float* s2 = out2 + (size_t)b * 64 * HW + px;
        const float* s3 = out3 + (size_t)b * 64 * HW + px;
        unsigned short v[128];
#pragma unroll
        for (int c = 0; c < 64; ++c) v[c] = f2bf(s2[(size_t)c * HW]);
#pragma unroll
        for (int c = 0; c < 64; ++c) v[64 + c] = f2bf(s3[(size_t)c * HW]);
        unsigned short* dst = tp + ((size_t)b * HW + px) * 128;
#pragma unroll
        for (int j = 0; j < 16; ++j)
            *(short8*)(dst + j * 8) = *(short8*)(v + j * 8);
    }
}

// ---------------- softmax over 4096 per batch ----------------
__global__ __launch_bounds__(256) void softmax_k(const float* __restrict__ logits,
                                                 float* __restrict__ attn)
{
    int b = blockIdx.x, tid = threadIdx.x;
    float lg[16];
#pragma unroll
    for (int k = 0; k < 16; ++k) lg[k] = logits[(size_t)b * HW + tid + (k << 8)];
    __shared__ float red[256];
    float m = -INFINITY;
#pragma unroll
    for (int k = 0; k < 16; ++k) m = fmaxf(m, lg[k]);
    red[tid] = m; __syncthreads();
    for (int s = 128; s > 0; s >>= 1) {
        if (tid < s) red[tid] = fmaxf(red[tid], red[tid + s]);
        __syncthreads();
    }
    m = red[0]; __syncthreads();
    float se = 0.f;
#pragma unroll
    for (int k = 0; k < 16; ++k) { lg[k] = __expf(lg[k] - m); se += lg[k]; }
    red[tid] = se; __syncthreads();
    for (int s = 128; s > 0; s >>= 1) {
        if (tid < s) red[tid] += red[tid + s];
        __syncthreads();
    }
    float inv = 1.0f / red[0];
#pragma unroll
    for (int k = 0; k < 16; ++k)
        attn[(size_t)b * HW + tid + (k << 8)] = lg[k] * inv;
}

// ---------------- weight prep: w[oc][ic][3][3] f32 -> wT[kk][oc][ic] bf16 ----------------
__global__ __launch_bounds__(256) void wprep_k(const float* w1, const float* w2, const float* w3,
                                               const float* wa, const float* wb2, const float* wp,
                                               unsigned short* __restrict__ wT)
{
    int blk = blockIdx.x;
    int base, ic, l2ic, off; const float* src;
    if      (blk < 32)  { base = 0;   ic = 64;  l2ic = 6; off = 0;      src = w1;  }
    else if (blk < 96)  { base = 32;  ic = 128; l2ic = 7; off = 73728;  src = w2;  }
    else if (blk < 160) { base = 96;  ic = 128; l2ic = 7; off = 221184; src = w3;  }
    else if (blk < 224) { base = 160; ic = 128; l2ic = 7; off = 368640; src = wa;  }
    else if (blk < 352) { base = 224; ic = 256; l2ic = 8; off = 516096; src = wb2; }
    else                { base = 352; ic = 128; l2ic = 7; off = 811008; src = wp;  }
    int pair = (blk - base) * 256 + threadIdx.x;
    int oc = pair >> l2ic, icx = pair & (ic - 1);
    const float* s = src + ((size_t)(oc * ic + icx)) * 9;
#pragma unroll
    for (int k = 0; k < 9; ++k)
        wT[(size_t)off + ((size_t)(k * 128 + oc)) * ic + icx] = f2bf(s[k]);
}

// ---------------- MFMA 32x32x16 implicit-GEMM conv: all-register, no LDS, no barriers ----------------
template<int IC, int STRIDE, int PS_IN, int CO_IN, int OPS, int OCO, bool ATTN>
__global__ __launch_bounds__(256, 4) void conv_k(
    const unsigned short* __restrict__ in,     // NHWC bf16
    const unsigned short* __restrict__ wTc,    // [9][128][IC] bf16
    const float* __restrict__ bias,
    const float* __restrict__ attn,
    unsigned short* __restrict__ out)
{
    constexpr int NIC16 = IC / 16;
    constexpr int LG = (IC == 64) ? 2 : (IC == 128) ? 3 : 4;
    constexpr int NS = 9 * NIC16;              // always even
    constexpr int NPX = (STRIDE == 1) ? 4096 : 1024;
    constexpr int WO = (STRIDE == 1) ? 64 : 32;

    int t = threadIdx.x;
    int wave = t >> 6, lane = t & 63;
    int l31 = lane & 31, lc2 = lane >> 5;
    int y0 = blockIdx.x, b = blockIdx.y;
    int col = l31;

    const unsigned short* abase = in + (size_t)b * HW * PS_IN + CO_IN + lc2 * 8;
    const unsigned short* bbase = wTc + (size_t)(wave * 32 + l31) * IC + lc2 * 8;
    const short8 zero8 = {0, 0, 0, 0, 0, 0, 0, 0};

    auto loadA = [&](int s, short8& d0, short8& d1) {
        int kk = s >> LG, ic16 = s & (NIC16 - 1);
        int ky = (kk * 11) >> 5, kx = kk - ky * 3;
        int cofs = ic16 * 16;
#pragma unroll
        for (int m = 0; m < 2; ++m) {
            int iy = (STRIDE == 1) ? (y0 + ky - 1) : (y0 * 4 + m * 2 + ky - 1);
            int ix = (STRIDE == 1) ? (m * 32 + col + kx - 1) : (col * 2 + kx - 1);
            bool ok = ((unsigned)iy < 64u) && ((unsigned)ix < 64u);
            const unsigned short* p = abase + (long)(iy * 64 + ix) * PS_IN + cofs;
            short8 v = ok ? *(const short8*)p : zero8;
            if (m == 0) d0 = v; else d1 = v;
        }
    };
    auto loadB = [&](int s) -> short8 {
        int kk = s >> LG, ic16 = s & (NIC16 - 1);
        return *(const short8*)(bbase + (size_t)kk * (128 * IC) + ic16 * 16);
    };

    f32x16 acc0 = (f32x16)0.0f, acc1 = (f32x16)0.0f;

    short8 A00, A01, A10, A11, B0, B1;
    loadA(0, A00, A01);
    B0 = loadB(0);

    for (int s = 0; s < NS; s += 2) {
        loadA(s + 1, A10, A11);
        B1 = loadB(s + 1);
        acc0 = __builtin_amdgcn_mfma_f32_32x32x16_bf16(A00, B0, acc0, 0, 0, 0);
        acc1 = __builtin_amdgcn_mfma_f32_32x32x16_bf16(A01, B0, acc1, 0, 0, 0);
        if (s + 2 < NS) {
            loadA(s + 2, A00, A01);
            B0 = loadB(s + 2);
        }
        acc0 = __builtin_amdgcn_mfma_f32_32x32x16_bf16(A10, B1, acc0, 0, 0, 0);
        acc1 = __builtin_amdgcn_mfma_f32_32x32x16_bf16(A11, B1, acc1, 0, 0, 0);
    }

    // ---- epilogue: bias + lrelu (+attn) -> NHWC bf16 ----
    int ocw = wave * 32 + l31;
    float bs = bias[ocw];
#pragma unroll
    for (int m = 0; m < 2; ++m) {
        f32x16 a = m ? acc1 : acc0;
#pragma unroll
        for (int r = 0; r < 16; ++r) {
            int pit = (r & 3) + 8 * (r >> 2) + 4 * lc2;
            int px = m * 32 + pit;
            int orow = (STRIDE == 1) ? y0 : (y0 * 2 + m);
            int ocol = (STRIDE == 1) ? px : pit;
            float v = a[r] + bs;
            v = (v >= 0.0f) ? v : 0.1f * v;
            if constexpr (ATTN) v *= attn[(size_t)b * HW + y0 * 64 + px];
            out[((size_t)b * NPX + (size_t)orow * WO + ocol) * OPS + OCO + ocw] = f2bf(v);
        }
    }
}

// ---------------- fused RoI + combine ----------------
__device__ __forceinline__ void acc8(float* a, const unsigned short* p, float w) {
    short8 v = *(const short8*)p;
#pragma unroll
    for (int k = 0; k < 8; ++k) a[k] = fmaf(w, b2f((unsigned short)v[k]), a[k]);
}

__global__ __launch_bounds__(256) void fuse_roi_k(const unsigned short* __restrict__ prevs,
                                                  const unsigned short* __restrict__ l12,
                                                  const unsigned short* __restrict__ auxb,
                                                  const unsigned short* __restrict__ bo2b,
                                                  float* __restrict__ o0,
                                                  float* __restrict__ o1,
                                                  float* __restrict__ o2)
{
    int idx = blockIdx.x * 256 + threadIdx.x;
    int j = idx & 31, i = (idx >> 5) & 31, ocg = (idx >> 10) & 15, b = idx >> 14;
    float a3[8] = {0,0,0,0,0,0,0,0}, aR[8] = {0,0,0,0,0,0,0,0};
    const unsigned short* pb = prevs + (size_t)b * HW * 128 + ocg * 8;
    const unsigned short* lb = l12 + (size_t)b * HW * 256 + 128 + ocg * 8;
#pragma unroll
    for (int sy = 0; sy < 2; ++sy) {
        float ys = (i + 0.25f + 0.5f * sy) * 1.96875f;
        int y0 = (int)ys;
        int y1 = min(y0 + 1, 63);
        float ly = ys - (float)y0, hy = 1.0f - ly;
#pragma unroll
        for (int sx = 0; sx < 2; ++sx) {
            float xs = (j + 0.25f + 0.5f * sx) * 1.96875f;
            int x0 = (int)xs;
            int x1 = min(x0 + 1, 63);
            float lx = xs - (float)x0, hx = 1.0f - lx;
            int p00 = y0 * 64 + x0, p01 = y0 * 64 + x1, p10 = y1 * 64 + x0, p11 = y1 * 64 + x1;
            float w00 = hy * hx, w01 = hy * lx, w10 = ly * hx, w11 = ly * lx;
            acc8(a3, pb + (size_t)p00 * 128, w00); acc8(a3, pb + (size_t)p01 * 128, w01);
            acc8(a3, pb + (size_t)p10 * 128, w10); acc8(a3, pb + (size_t)p11 * 128, w11);
            acc8(aR, lb + (size_t)p00 * 256, w00); acc8(aR, lb + (size_t)p01 * 256, w01);
            acc8(aR, lb + (size_t)p10 * 256, w10); acc8(aR, lb + (size_t)p11 * 256, w11);
        }
    }
    int p32 = i * 32 + j;
    const unsigned short* ax = auxb + ((size_t)(b * 1024 + p32)) * 128 + ocg * 8;
    const unsigned short* b2 = bo2b + ((size_t)(b * 1024 + p32)) * 128 + ocg * 8;
#pragma unroll
    for (int k = 0; k < 8; ++k) {
        int oc = ocg * 8 + k;
        size_t ob = ((size_t)(b * 128 + oc)) * 1024 + p32;
        float v3 = a3[k] * 0.25f;
        float v2 = b2f(b2[k]);
        o2[ob] = v3;
        o1[ob] = v2;
        o0[ob] = aR[k] * 0.25f + b2f(ax[k]) + v2 + v3;
    }
}

// ---------------- launch ----------------
extern "C" void kernel_launch(void* const* d_in, const int* in_sizes, int n_in,
                              void* d_out, int out_size, void* d_ws, size_t ws_size,
                              hipStream_t stream)
{
    const float* out1  = (const float*)d_in[0];
    const float* out2  = (const float*)d_in[1];
    const float* out3  = (const float*)d_in[2];
    const float* w1    = (const float*)d_in[3];  const float* b1    = (const float*)d_in[4];
    const float* w2    = (const float*)d_in[5];  const float* b2    = (const float*)d_in[6];
    const float* w3    = (const float*)d_in[7];  const float* b3    = (const float*)d_in[8];
    const float* w_aux = (const float*)d_in[9];  const float* b_aux = (const float*)d_in[10];
    const float* w_b2  = (const float*)d_in[11]; const float* b_b2  = (const float*)d_in[12];
    const float* w_prev= (const float*)d_in[13]; const float* b_prev= (const float*)d_in[14];
    const float* lin_w = (const float*)d_in[15]; const float* lin_b = (const float*)d_in[16];

    char* ws = (char*)d_ws;
    unsigned short* l12cat = (unsigned short*)(ws);                 // [B][4096][256] bf16, 64 MB
    unsigned short* l3     = (unsigned short*)(ws + 67108864);      // [B][4096][128] bf16, 32 MB
    unsigned short* prevs  = l3;                                     // reused after aux conv
    unsigned short* auxb   = (unsigned short*)(ws + 100663296);     // [B][1024][128] bf16, 8 MB
    unsigned short* bo2b   = (unsigned short*)(ws + 109051904);     // [B][1024][128] bf16, 8 MB
    float* attn   = (float*)(ws + 117440512);                        // 512 KB
    float* logits = (float*)(ws + 117964800);                        // 512 KB
    unsigned short* wT = (unsigned short*)(ws + 118489088);          // 1.92 MB

    // t1/tp scratch live in d_out (48 MB); fully consumed by the prev conv
    // before fuse_roi_k overwrites d_out with the real outputs.
    unsigned short* t1 = (unsigned short*)d_out;                     // [B][4096][64] bf16
    unsigned short* tp = t1 + (size_t)B * HW * 64;                   // [B][4096][128] bf16

    float* o0 = (float*)d_out;
    float* o1 = o0 + (size_t)B * 128 * 1024;
    float* o2 = o1 + (size_t)B * 128 * 1024;

    wprep_k<<<dim3(416), dim3(256), 0, stream>>>(w1, w2, w3, w_aux, w_b2, w_prev, wT);
    tr_k<<<dim3(16, B, 2), dim3(256), 0, stream>>>(out1, out2, out3, lin_w, lin_b, t1, tp, logits);
    softmax_k<<<dim3(B), dim3(256), 0, stream>>>(logits, attn);

    // l1 = lrelu(conv(out1,w1)) -> l12cat ch 0..127
    conv_k<64, 1, 64, 0, 256, 0, false><<<dim3(64, B), dim3(256), 0, stream>>>(
        t1, wT + 0, b1, nullptr, l12cat);
    // l2 = lrelu(conv(l1,w2)) -> l12cat ch 128..255
    conv_k<128, 1, 256, 0, 256, 128, false><<<dim3(64, B), dim3(256), 0, stream>>>(
        l12cat, wT + 73728, b2, nullptr, l12cat);
    // l3 = lrelu(conv(l2,w3))
    conv_k<128, 1, 256, 128, 128, 0, false><<<dim3(64, B), dim3(256), 0, stream>>>(
        l12cat, wT + 221184, b3, nullptr, l3);
    // aux = lrelu(conv(l3,w_aux,s2))
    conv_k<128, 2, 128, 0, 128, 0, false><<<dim3(16, B), dim3(256), 0, stream>>>(
        l3, wT + 368640, b_aux, nullptr, auxb);
    // block_out2 = lrelu(conv(concat(l1,l2),w_b2,s2))
    conv_k<256, 2, 256, 0, 128, 0, false><<<dim3(16, B), dim3(256), 0, stream>>>(
        l12cat, wT + 516096, b_b2, nullptr, bo2b);
    // prevs = lrelu(conv(concat(out2,out3),w_prev)) * attn   (overwrites l3 slot)
    conv_k<128, 1, 128, 0, 128, 0, true><<<dim3(64, B), dim3(256), 0, stream>>>(
        tp, wT + 811008, b_prev, attn, prevs);

    fuse_roi_k<<<dim3(2048), dim3(256), 0, stream>>>(prevs, l12cat, auxb, bo2b, o0, o1, o2);
}

// Round 6
// 659.700 us; speedup vs baseline: 1.8032x; 1.8032x over previous
//
#include <hip/hip_runtime.h>
#include <hip/hip_bf16.h>

typedef __attribute__((ext_vector_type(8))) short short8;
typedef __attribute__((ext_vector_type(4))) float f32x4;

constexpr int B = 32, C = 64, HW = 4096;

__device__ __forceinline__ unsigned short f2bf(float f) {
    __hip_bfloat16 h = __float2bfloat16(f);
    unsigned short u; __builtin_memcpy(&u, &h, 2); return u;
}
__device__ __forceinline__ float b2f(unsigned short u) {
    unsigned int t = ((unsigned int)u) << 16; float f; __builtin_memcpy(&f, &t, 4); return f;
}
__device__ __forceinline__ void gllds16(const void* g, void* l) {
    __builtin_amdgcn_global_load_lds((const __attribute__((address_space(1))) unsigned int*)g,
                                     (__attribute__((address_space(3))) unsigned int*)l, 16, 0, 0);
}
__device__ __forceinline__ void cfence() { asm volatile("" ::: "memory"); }
__device__ __forceinline__ void vmcnt2() { asm volatile("s_waitcnt vmcnt(2)" ::: "memory"); }
__device__ __forceinline__ void vmcnt0() { asm volatile("s_waitcnt vmcnt(0)" ::: "memory"); }

// ---------------- NCHW f32 -> NHWC bf16 transpose (+ fused attention logits) ----------------
__global__ __launch_bounds__(256) void tr_k(const float* __restrict__ out1,
                                            const float* __restrict__ out2,
                                            const float* __restrict__ out3,
                                            const float* __restrict__ lin_w,
                                            const float* __restrict__ lin_b,
                                            unsigned short* __restrict__ t1,
                                            unsigned short* __restrict__ tp,
                                            float* __restrict__ logits)
{
    int t = threadIdx.x;
    int px = blockIdx.x * 256 + t;
    int b = blockIdx.y;
    if (blockIdx.z == 0) {
        const float* src = out1 + (size_t)b * 64 * HW + px;
        const float* lwp = lin_w + (size_t)px * 64;
        float acc = lin_b[px];
        unsigned short v[64];
#pragma unroll
        for (int c = 0; c < 64; c += 4) {
            float4 w4 = *(const float4*)(lwp + c);
            float x0 = src[(size_t)c * HW];
            float x1 = src[(size_t)(c + 1) * HW];
            float x2 = src[(size_t)(c + 2) * HW];
            float x3 = src[(size_t)(c + 3) * HW];
            acc = fmaf(x0, w4.x, acc); acc = fmaf(x1, w4.y, acc);
            acc = fmaf(x2, w4.z, acc); acc = fmaf(x3, w4.w, acc);
            v[c] = f2bf(x0); v[c + 1] = f2bf(x1); v[c + 2] = f2bf(x2); v[c + 3] = f2bf(x3);
        }
        unsigned short* dst = t1 + ((size_t)b * HW + px) * 64;
#pragma unroll
        for (int j = 0; j < 8; ++j)
            *(short8*)(dst + j * 8) = *(short8*)(v + j * 8);
        logits[(size_t)b * HW + px] = acc;
    } else {
        const float* s2 = out2 + (size_t)b * 64 * HW + px;
        const float* s3 = out3 + (size_t)b * 64 * HW + px;
        unsigned short v[128];
#pragma unroll
        for (int c = 0; c < 64; ++c) v[c] = f2bf(s2[(size_t)c * HW]);
#pragma unroll
        for (int c = 0; c < 64; ++c) v[64 + c] = f2bf(s3[(size_t)c * HW]);
        unsigned short* dst = tp + ((size_t)b * HW + px) * 128;
#pragma unroll
        for (int j = 0; j < 16; ++j)
            *(short8*)(dst + j * 8) = *(short8*)(v + j * 8);
    }
}

// ---------------- softmax over 4096 per batch ----------------
__global__ __launch_bounds__(256) void softmax_k(const float* __restrict__ logits,
                                                 float* __restrict__ attn)
{
    int b = blockIdx.x, tid = threadIdx.x;
    float lg[16];
#pragma unroll
    for (int k = 0; k < 16; ++k) lg[k] = logits[(size_t)b * HW + tid + (k << 8)];
    __shared__ float red[256];
    float m = -INFINITY;
#pragma unroll
    for (int k = 0; k < 16; ++k) m = fmaxf(m, lg[k]);
    red[tid] = m; __syncthreads();
    for (int s = 128; s > 0; s >>= 1) {
        if (tid < s) red[tid] = fmaxf(red[tid], red[tid + s]);
        __syncthreads();
    }
    m = red[0]; __syncthreads();
    float se = 0.f;
#pragma unroll
    for (int k = 0; k < 16; ++k) { lg[k] = __expf(lg[k] - m); se += lg[k]; }
    red[tid] = se; __syncthreads();
    for (int s = 128; s > 0; s >>= 1) {
        if (tid < s) red[tid] += red[tid + s];
        __syncthreads();
    }
    float inv = 1.0f / red[0];
#pragma unroll
    for (int k = 0; k < 16; ++k)
        attn[(size_t)b * HW + tid + (k << 8)] = lg[k] * inv;
}

// ---------------- weight prep: w[oc][ic][3][3] f32 -> wT[kk][oc][ic] bf16 ----------------
__global__ __launch_bounds__(256) void wprep_k(const float* w1, const float* w2, const float* w3,
                                               const float* wa, const float* wb2, const float* wp,
                                               unsigned short* __restrict__ wT)
{
    int blk = blockIdx.x;
    int base, ic, l2ic, off; const float* src;
    if      (blk < 32)  { base = 0;   ic = 64;  l2ic = 6; off = 0;      src = w1;  }
    else if (blk < 96)  { base = 32;  ic = 128; l2ic = 7; off = 73728;  src = w2;  }
    else if (blk < 160) { base = 96;  ic = 128; l2ic = 7; off = 221184; src = w3;  }
    else if (blk < 224) { base = 160; ic = 128; l2ic = 7; off = 368640; src = wa;  }
    else if (blk < 352) { base = 224; ic = 256; l2ic = 8; off = 516096; src = wb2; }
    else                { base = 352; ic = 128; l2ic = 7; off = 811008; src = wp;  }
    int pair = (blk - base) * 256 + threadIdx.x;
    int oc = pair >> l2ic, icx = pair & (ic - 1);
    const float* s = src + ((size_t)(oc * ic + icx)) * 9;
#pragma unroll
    for (int k = 0; k < 9; ++k)
        wT[(size_t)off + ((size_t)(k * 128 + oc)) * ic + icx] = f2bf(s[k]);
}

// ---------------- MFMA implicit-GEMM conv: A global->reg prefetch, B LDS dbuf, counted vmcnt ----------------
template<int IC, int STRIDE, int PS_IN, int CO_IN, int OPS, int OCO, bool ATTN>
__global__ __launch_bounds__(256, 4) void conv_k(
    const unsigned short* __restrict__ in,     // NHWC bf16
    const unsigned short* __restrict__ wTc,    // [9][128][IC] bf16
    const float* __restrict__ bias,
    const float* __restrict__ attn,
    unsigned short* __restrict__ out)
{
    constexpr int NICG = IC / 32;
    constexpr int LG = (IC == 64) ? 1 : (IC == 128) ? 2 : 3;
    constexpr int NS = 9 * NICG;               // always even
    constexpr int NPX = (STRIDE == 1) ? 4096 : 1024;
    constexpr int WO = (STRIDE == 1) ? 64 : 32;

    __shared__ char bsm[2][8192];

    int t = threadIdx.x;
    int wave = t >> 6, lane = t & 63;
    int mw = wave & 1, nw = wave >> 1;
    int l15 = lane & 15, lc = lane >> 4;
    int y0 = blockIdx.x, b = blockIdx.y;

    // B LDS read byte-offsets (swizzled: slot c' = c ^ ((oc>>1)&3))
    int bofs[4];
#pragma unroll
    for (int nf = 0; nf < 4; ++nf) {
        int oc = nw * 64 + nf * 16 + l15;
        bofs[nf] = oc * 64 + ((lc ^ ((oc >> 1) & 3)) << 4);
    }
    // staging source (thread t fills LDS slot t and slot 256+t; inverse-swizzled src)
    int oc0 = t >> 2;
    int c0 = (t & 3) ^ ((oc0 >> 1) & 3);
    const unsigned short* wsrc = wTc + oc0 * IC + c0 * 8;
    char* lbase = &bsm[0][0] + (wave << 10);

    const unsigned short* base_b = in + (size_t)b * HW * PS_IN + CO_IN + (lc << 3);
    int col[2];
#pragma unroll
    for (int f = 0; f < 2; ++f)
        col[f] = (STRIDE == 1) ? (mw * 32 + f * 16 + l15) : (f * 16 + l15);

    const short8 zero8 = {0, 0, 0, 0, 0, 0, 0, 0};

    f32x4 acc[2][4];
#pragma unroll
    for (int f = 0; f < 2; ++f)
#pragma unroll
        for (int nf = 0; nf < 4; ++nf) acc[f][nf] = (f32x4)0.0f;

    auto stage = [&](int s, int buf) {
        int kk = s >> LG, icg = s & (NICG - 1);
        const unsigned short* p = wsrc + (size_t)kk * 128 * IC + icg * 32;
        char* d = lbase + buf * 8192;
        gllds16(p, d);
        gllds16(p + 64 * IC, d + 4096);
    };
    auto loadA = [&](int s, short8& d0, short8& d1) {
        int kk = s >> LG, icg = s & (NICG - 1);
        int ky = (kk * 11) >> 5;
        int kx = kk - ky * 3;
        int iy = (STRIDE == 1) ? (y0 + ky - 1) : ((y0 * 2 + mw) * 2 + ky - 1);
        bool yok = (unsigned)iy < 64u;
        const unsigned short* prow = base_b + (long)iy * (64 * PS_IN) + icg * 32;
#pragma unroll
        for (int f = 0; f < 2; ++f) {
            int ix = (STRIDE == 1) ? (col[f] + kx - 1) : (2 * col[f] + kx - 1);
            bool ok = yok && ((unsigned)ix < 64u);
            const short8* ap = (const short8*)(prow + (long)ix * PS_IN);
            short8 v = ok ? *ap : zero8;
            if (f == 0) d0 = v; else d1 = v;
        }
    };
    auto body = [&](int s, int cur, short8& Ac0, short8& Ac1, short8& An0, short8& An1) {
        bool more = (s + 1 < NS);
        if (more) {
            stage(s + 1, cur ^ 1);       // glds issued FIRST (oldest in queue)
            cfence();                    // pin order: glds before A-loads
            loadA(s + 1, An0, An1);      // 2 global->reg loads (newest in queue)
        }
        const char* bb_base = &bsm[0][0] + cur * 8192;
        short8 bb[4];
#pragma unroll
        for (int nf = 0; nf < 4; ++nf)
            bb[nf] = *(const short8*)(bb_base + bofs[nf]);
#pragma unroll
        for (int nf = 0; nf < 4; ++nf) {
            acc[0][nf] = __builtin_amdgcn_mfma_f32_16x16x32_bf16(Ac0, bb[nf], acc[0][nf], 0, 0, 0);
            acc[1][nf] = __builtin_amdgcn_mfma_f32_16x16x32_bf16(Ac1, bb[nf], acc[1][nf], 0, 0, 0);
        }
        if (more) {
            vmcnt2();                    // drain stage(s+1) glds; keep the 2 newer A-loads in flight
            __builtin_amdgcn_s_barrier();
        }
    };

    short8 Aa0, Aa1, Ab0, Ab1;
    stage(0, 0);
    loadA(0, Aa0, Aa1);
    vmcnt0();
    __builtin_amdgcn_s_barrier();

    for (int s = 0; s < NS; s += 2) {
        body(s,     0, Aa0, Aa1, Ab0, Ab1);
        body(s + 1, 1, Ab0, Ab1, Aa0, Aa1);
    }

    // epilogue: bias + lrelu (+attn) -> NHWC bf16
    int orow = (STRIDE == 1) ? y0 : (y0 * 2 + mw);
    float bs[4];
#pragma unroll
    for (int nf = 0; nf < 4; ++nf) bs[nf] = bias[nw * 64 + nf * 16 + l15];
#pragma unroll
    for (int f = 0; f < 2; ++f) {
#pragma unroll
        for (int r = 0; r < 4; ++r) {
            int pxcol = ((STRIDE == 1) ? mw * 32 : 0) + f * 16 + (lc << 2) + r;
            float av = 1.0f;
            if constexpr (ATTN) av = attn[(size_t)b * HW + y0 * 64 + pxcol];
            size_t obase = ((size_t)b * NPX + (size_t)orow * WO + pxcol) * OPS + OCO;
#pragma unroll
            for (int nf = 0; nf < 4; ++nf) {
                int oc = nw * 64 + nf * 16 + l15;
                float v = acc[f][nf][r] + bs[nf];
                v = (v >= 0.0f) ? v : 0.1f * v;
                if constexpr (ATTN) v *= av;
                out[obase + oc] = f2bf(v);
            }
        }
    }
}

// ---------------- fused RoI + combine ----------------
__device__ __forceinline__ void acc8(float* a, const unsigned short* p, float w) {
    short8 v = *(const short8*)p;
#pragma unroll
    for (int k = 0; k < 8; ++k) a[k] = fmaf(w, b2f((unsigned short)v[k]), a[k]);
}

__global__ __launch_bounds__(256) void fuse_roi_k(const unsigned short* __restrict__ prevs,
                                                  const unsigned short* __restrict__ l12,
                                                  const unsigned short* __restrict__ auxb,
                                                  const unsigned short* __restrict__ bo2b,
                                                  float* __restrict__ o0,
                                                  float* __restrict__ o1,
                                                  float* __restrict__ o2)
{
    int idx = blockIdx.x * 256 + threadIdx.x;
    int j = idx & 31, i = (idx >> 5) & 31, ocg = (idx >> 10) & 15, b = idx >> 14;
    float a3[8] = {0,0,0,0,0,0,0,0}, aR[8] = {0,0,0,0,0,0,0,0};
    const unsigned short* pb = prevs + (size_t)b * HW * 128 + ocg * 8;
    const unsigned short* lb = l12 + (size_t)b * HW * 256 + 128 + ocg * 8;
#pragma unroll
    for (int sy = 0; sy < 2; ++sy) {
        float ys = (i + 0.25f + 0.5f * sy) * 1.96875f;
        int y0 = (int)ys;
        int y1 = min(y0 + 1, 63);
        float ly = ys - (float)y0, hy = 1.0f - ly;
#pragma unroll
        for (int sx = 0; sx < 2; ++sx) {
            float xs = (j + 0.25f + 0.5f * sx) * 1.96875f;
            int x0 = (int)xs;
            int x1 = min(x0 + 1, 63);
            float lx = xs - (float)x0, hx = 1.0f - lx;
            int p00 = y0 * 64 + x0, p01 = y0 * 64 + x1, p10 = y1 * 64 + x0, p11 = y1 * 64 + x1;
            float w00 = hy * hx, w01 = hy * lx, w10 = ly * hx, w11 = ly * lx;
            acc8(a3, pb + (size_t)p00 * 128, w00); acc8(a3, pb + (size_t)p01 * 128, w01);
            acc8(a3, pb + (size_t)p10 * 128, w10); acc8(a3, pb + (size_t)p11 * 128, w11);
            acc8(aR, lb + (size_t)p00 * 256, w00); acc8(aR, lb + (size_t)p01 * 256, w01);
            acc8(aR, lb + (size_t)p10 * 256, w10); acc8(aR, lb + (size_t)p11 * 256, w11);
        }
    }
    int p32 = i * 32 + j;
    const unsigned short* ax = auxb + ((size_t)(b * 1024 + p32)) * 128 + ocg * 8;
    const unsigned short* b2 = bo2b + ((size_t)(b * 1024 + p32)) * 128 + ocg * 8;
#pragma unroll
    for (int k = 0; k < 8; ++k) {
        int oc = ocg * 8 + k;
        size_t ob = ((size_t)(b * 128 + oc)) * 1024 + p32;
        float v3 = a3[k] * 0.25f;
        float v2 = b2f(b2[k]);
        o2[ob] = v3;
        o1[ob] = v2;
        o0[ob] = aR[k] * 0.25f + b2f(ax[k]) + v2 + v3;
    }
}

// ---------------- launch ----------------
extern "C" void kernel_launch(void* const* d_in, const int* in_sizes, int n_in,
                              void* d_out, int out_size, void* d_ws, size_t ws_size,
                              hipStream_t stream)
{
    const float* out1  = (const float*)d_in[0];
    const float* out2  = (const float*)d_in[1];
    const float* out3  = (const float*)d_in[2];
    const float* w1    = (const float*)d_in[3];  const float* b1    = (const float*)d_in[4];
    const float* w2    = (const float*)d_in[5];  const float* b2    = (const float*)d_in[6];
    const float* w3    = (const float*)d_in[7];  const float* b3    = (const float*)d_in[8];
    const float* w_aux = (const float*)d_in[9];  const float* b_aux = (const float*)d_in[10];
    const float* w_b2  = (const float*)d_in[11]; const float* b_b2  = (const float*)d_in[12];
    const float* w_prev= (const float*)d_in[13]; const float* b_prev= (const float*)d_in[14];
    const float* lin_w = (const float*)d_in[15]; const float* lin_b = (const float*)d_in[16];

    char* ws = (char*)d_ws;
    unsigned short* l12cat = (unsigned short*)(ws);                 // [B][4096][256] bf16, 64 MB
    unsigned short* l3     = (unsigned short*)(ws + 67108864);      // [B][4096][128] bf16, 32 MB
    unsigned short* prevs  = l3;                                     // reused after aux conv
    unsigned short* auxb   = (unsigned short*)(ws + 100663296);     // [B][1024][128] bf16, 8 MB
    unsigned short* bo2b   = (unsigned short*)(ws + 109051904);     // [B][1024][128] bf16, 8 MB
    float* attn   = (float*)(ws + 117440512);                        // 512 KB
    float* logits = (float*)(ws + 117964800);                        // 512 KB
    unsigned short* wT = (unsigned short*)(ws + 118489088);          // 1.92 MB

    // t1/tp scratch live in d_out (48 MB); fully consumed by the prev conv
    // before fuse_roi_k overwrites d_out with the real outputs.
    unsigned short* t1 = (unsigned short*)d_out;                     // [B][4096][64] bf16
    unsigned short* tp = t1 + (size_t)B * HW * 64;                   // [B][4096][128] bf16

    float* o0 = (float*)d_out;
    float* o1 = o0 + (size_t)B * 128 * 1024;
    float* o2 = o1 + (size_t)B * 128 * 1024;

    wprep_k<<<dim3(416), dim3(256), 0, stream>>>(w1, w2, w3, w_aux, w_b2, w_prev, wT);
    tr_k<<<dim3(16, B, 2), dim3(256), 0, stream>>>(out1, out2, out3, lin_w, lin_b, t1, tp, logits);
    softmax_k<<<dim3(B), dim3(256), 0, stream>>>(logits, attn);

    // l1 = lrelu(conv(out1,w1)) -> l12cat ch 0..127
    conv_k<64, 1, 64, 0, 256, 0, false><<<dim3(64, B), dim3(256), 0, stream>>>(
        t1, wT + 0, b1, nullptr, l12cat);
    // l2 = lrelu(conv(l1,w2)) -> l12cat ch 128..255
    conv_k<128, 1, 256, 0, 256, 128, false><<<dim3(64, B), dim3(256), 0, stream>>>(
        l12cat, wT + 73728, b2, nullptr, l12cat);
    // l3 = lrelu(conv(l2,w3))
    conv_k<128, 1, 256, 128, 128, 0, false><<<dim3(64, B), dim3(256), 0, stream>>>(
        l12cat, wT + 221184, b3, nullptr, l3);
    // aux = lrelu(conv(l3,w_aux,s2))
    conv_k<128, 2, 128, 0, 128, 0, false><<<dim3(16, B), dim3(256), 0, stream>>>(
        l3, wT + 368640, b_aux, nullptr, auxb);
    // block_out2 = lrelu(conv(concat(l1,l2),w_b2,s2))
    conv_k<256, 2, 256, 0, 128, 0, false><<<dim3(16, B), dim3(256), 0, stream>>>(
        l12cat, wT + 516096, b_b2, nullptr, bo2b);
    // prevs = lrelu(conv(concat(out2,out3),w_prev)) * attn   (overwrites l3 slot)
    conv_k<128, 1, 128, 0, 128, 0, true><<<dim3(64, B), dim3(256), 0, stream>>>(
        tp, wT + 811008, b_prev, attn, prevs);

    fuse_roi_k<<<dim3(2048), dim3(256), 0, stream>>>(prevs, l12cat, auxb, bo2b, o0, o1, o2);
}